// Round 11
// baseline (464.567 us; speedup 1.0000x reference)
//
#include <hip/hip_runtime.h>
#include <cstdint>
#include <cstddef>

#define SEQ 2048
#define TILES 16
#define FRAG_SHORTS 12288                 // bf16 per 128-col tile (8 st * 3 frag * 64 lane * 8)
#define FRAG_BYTES  24576
#define PSTRIDE 36                        // shorts per row of wave-private transpose buf

typedef __attribute__((ext_vector_type(8))) short bf16x8;
typedef __attribute__((ext_vector_type(4))) float f32x4;
typedef __attribute__((ext_vector_type(4))) short short4v;
typedef __attribute__((ext_vector_type(2))) unsigned uint2v;

__device__ __forceinline__ short f2bf(float f) {
    union { float f; unsigned u; } a; a.f = f;
    unsigned r = a.u + 0x7fffu + ((a.u >> 16) & 1u);
    return (short)(r >> 16);
}
__device__ __forceinline__ float clip5(float v) { return fminf(fmaxf(v, -5.0f), 5.0f); }
__device__ __forceinline__ float bflo2f(unsigned u) { union { unsigned u; float f; } a; a.u = u << 16; return a.f; }
__device__ __forceinline__ float bfhi2f(unsigned u) { union { unsigned u; float f; } a; a.u = u & 0xffff0000u; return a.f; }

#define QS_C  (0.125f * 1.4426950408889634f)
#define PQS_C (0.17677669529663687f * 1.4426950408889634f)
#define SHIFT_C 28.853900817779268f

// ---- prepass: K/PK f32 -> clipped bf16 in MFMA A-fragment order ----
// ws layout: [bh(32)][tile(16)][st(8)][frag(3)][lane(64)][j(8)]
__global__ __launch_bounds__(256)
void prep_kernel(const float* __restrict__ Kp, const float* __restrict__ PKp,
                 short* __restrict__ wsK)
{
    int id = blockIdx.x * 256 + threadIdx.x;   // 65536 rows * 24 float4
    int q = id % 24;
    int row = id / 24;            // bh*2048 + col
    int bh = row >> 11;
    int col = row & 2047;
    int tile = col >> 7;
    int st = (col >> 4) & 7;
    int l15 = col & 15;
    float4 v;
    int f, dd;
    if (q < 16) {                 // keys: 16 float4 per row
        v = reinterpret_cast<const float4*>(Kp)[(size_t)row * 16 + q];
        f = q >> 3;
        dd = (q & 7) * 4;
    } else {                      // pos_key: 8 float4 per row
        v = reinterpret_cast<const float4*>(PKp)[(size_t)row * 8 + (q - 16)];
        f = 2;
        dd = (q - 16) * 4;
    }
    int ll = l15 | ((dd >> 3) << 4);
    int j = dd & 7;
    short4v s4;
    s4[0] = f2bf(clip5(v.x)); s4[1] = f2bf(clip5(v.y));
    s4[2] = f2bf(clip5(v.z)); s4[3] = f2bf(clip5(v.w));
    *reinterpret_cast<short4v*>(wsK + ((size_t)bh * TILES + tile) * FRAG_SHORTS
                                + (((st * 3 + f) * 64 + ll) << 3) + j) = s4;
}

// ---- main ws kernel: 512 persistent blocks x 512 thr (8 waves), 4 strips of
// 32 q rows each. Wave: rg=w&1 row half, cs=w>>1 col quarter.
// Per strip: barrier-free reg-staged compute sweep (pk in VGPRs) -> 1-barrier
// reduce -> prefetch next strip's K/Q (BEFORE stores, so the next MFMA's
// waitcnt is vmcnt(32), keeping stores in flight) -> 32 contiguous nt stores.
__global__ __launch_bounds__(512, 4)
void attn_ws_kernel(const float* __restrict__ Qp, const float* __restrict__ PQp,
                    const int* __restrict__ maskp, const short* __restrict__ wsK,
                    float* __restrict__ out)
{
    __shared__ float lds_madd[SEQ];           // (mask? -1e30:0) - SHIFT
    __shared__ short lds_p[8][16 * PSTRIDE];  // wave-private transpose bufs
    __shared__ float sred[2][8][16];          // parity-buffered row-sum partials
    __shared__ float lds_inv[8][16];          // per-wave 1/rowsum

    // XCD-aware mapping: p%8 = XCD; 4 bh x 16 q-groups (128 rows) per XCD.
    const int p = blockIdx.x;
    const int x = p & 7;
    const int slot = p >> 3;               // 0..63
    const int bh = x + 8 * (slot >> 4);    // {x, x+8, x+16, x+24}
    const int qg = slot & 15;              // 0..15

    const int tid = threadIdx.x;
    const int lane = tid & 63;
    const int w = tid >> 6;
    const int l15 = lane & 15;
    const int l4 = lane >> 4;
    const int rg = w & 1;
    const int cs = w >> 1;

    const float* Qb  = Qp  + (size_t)bh * (SEQ * 64);
    const float* PQb = PQp + (size_t)bh * (SEQ * 32);
    const int*   mb  = maskp + (size_t)(bh >> 4) * SEQ;
    float* outb = out + (size_t)bh * SEQ * SEQ;

    // ---- mask -> LDS once per block ----
    #pragma unroll
    for (int i = 0; i < SEQ / 512; ++i) {
        int idx = i * 512 + tid;
        lds_madd[idx] = (mb[idx] ? -1e30f : 0.0f) - SHIFT_C;
    }

    const short* kf = wsK + (size_t)bh * (TILES * FRAG_SHORTS);
    const int st0 = cs * 2, st1 = st0 + 1;
    const int oa0 = ((st0 * 3 + 0) * 64 + lane) * 8;
    const int oa1 = ((st0 * 3 + 1) * 64 + lane) * 8;
    const int oa2 = ((st0 * 3 + 2) * 64 + lane) * 8;
    const int ob0 = ((st1 * 3 + 0) * 64 + lane) * 8;
    const int ob1 = ((st1 * 3 + 1) * 64 + lane) * 8;
    const int ob2 = ((st1 * 3 + 2) * 64 + lane) * 8;

    // load + convert Q/PQ fragments for a strip
#define LDQ(S)                                                                  \
    do {                                                                        \
        const int qrow_ = qg * 128 + (S) * 32 + rg * 16 + l15;                  \
        _Pragma("unroll")                                                       \
        for (int f = 0; f < 2; ++f) {                                           \
            const float* src = Qb + (size_t)qrow_ * 64 + f * 32 + l4 * 8;       \
            bf16x8 v;                                                           \
            _Pragma("unroll")                                                   \
            for (int j = 0; j < 8; ++j) v[j] = f2bf(clip5(src[j]) * QS_C);      \
            qa[f] = v;                                                          \
        }                                                                       \
        {                                                                       \
            const float* src = PQb + (size_t)qrow_ * 32 + l4 * 8;               \
            bf16x8 v;                                                           \
            _Pragma("unroll")                                                   \
            for (int j = 0; j < 8; ++j) v[j] = f2bf(clip5(src[j]) * PQS_C);     \
            qa[2] = v;                                                          \
        }                                                                       \
    } while (0)

#define LDK_T0()                                                                \
    do {                                                                        \
        a0 = *reinterpret_cast<const bf16x8*>(kf + oa0);                        \
        a1 = *reinterpret_cast<const bf16x8*>(kf + oa1);                        \
        a2 = *reinterpret_cast<const bf16x8*>(kf + oa2);                        \
        b0 = *reinterpret_cast<const bf16x8*>(kf + ob0);                        \
        b1 = *reinterpret_cast<const bf16x8*>(kf + ob1);                        \
        b2 = *reinterpret_cast<const bf16x8*>(kf + ob2);                        \
    } while (0)

    bf16x8 qa[3];
    bf16x8 a0, a1, a2, b0, b1, b2;
    LDQ(0);
    LDK_T0();
    __syncthreads();   // lds_madd ready

    #pragma unroll 1
    for (int strip = 0; strip < 4; ++strip) {
        unsigned pk[64];   // packed bf16 P: [tile(16)][sti(2)][pair(2)]
        float ssum = 0.0f;

        // ---- barrier-free compute sweep (fully unrolled; depth-1 K prefetch) ----
        #pragma unroll
        for (int t = 0; t < TILES; ++t) {
            f32x4 acc0 = {0.f, 0.f, 0.f, 0.f};
            f32x4 acc1 = {0.f, 0.f, 0.f, 0.f};
            acc0 = __builtin_amdgcn_mfma_f32_16x16x32_bf16(a0, qa[0], acc0, 0, 0, 0);
            acc0 = __builtin_amdgcn_mfma_f32_16x16x32_bf16(a1, qa[1], acc0, 0, 0, 0);
            acc0 = __builtin_amdgcn_mfma_f32_16x16x32_bf16(a2, qa[2], acc0, 0, 0, 0);
            acc1 = __builtin_amdgcn_mfma_f32_16x16x32_bf16(b0, qa[0], acc1, 0, 0, 0);
            acc1 = __builtin_amdgcn_mfma_f32_16x16x32_bf16(b1, qa[1], acc1, 0, 0, 0);
            acc1 = __builtin_amdgcn_mfma_f32_16x16x32_bf16(b2, qa[2], acc1, 0, 0, 0);
            if (t < TILES - 1) {
                const short* kt = kf + (size_t)(t + 1) * FRAG_SHORTS;
                a0 = *reinterpret_cast<const bf16x8*>(kt + oa0);
                a1 = *reinterpret_cast<const bf16x8*>(kt + oa1);
                a2 = *reinterpret_cast<const bf16x8*>(kt + oa2);
                b0 = *reinterpret_cast<const bf16x8*>(kt + ob0);
                b1 = *reinterpret_cast<const bf16x8*>(kt + ob1);
                b2 = *reinterpret_cast<const bf16x8*>(kt + ob2);
            }
            f32x4 m0 = *reinterpret_cast<const f32x4*>(&lds_madd[t * 128 + st0 * 16 + l4 * 4]);
            f32x4 m1 = *reinterpret_cast<const f32x4*>(&lds_madd[t * 128 + st1 * 16 + l4 * 4]);
            float e00 = exp2f(acc0[0] + m0[0]);
            float e01 = exp2f(acc0[1] + m0[1]);
            float e02 = exp2f(acc0[2] + m0[2]);
            float e03 = exp2f(acc0[3] + m0[3]);
            float e10 = exp2f(acc1[0] + m1[0]);
            float e11 = exp2f(acc1[1] + m1[1]);
            float e12 = exp2f(acc1[2] + m1[2]);
            float e13 = exp2f(acc1[3] + m1[3]);
            ssum += ((e00 + e01) + (e02 + e03)) + ((e10 + e11) + (e12 + e13));
            unsigned u0, u1, u2, u3;
            asm("v_cvt_pk_bf16_f32 %0, %1, %2" : "=v"(u0) : "v"(e00), "v"(e01));
            asm("v_cvt_pk_bf16_f32 %0, %1, %2" : "=v"(u1) : "v"(e02), "v"(e03));
            asm("v_cvt_pk_bf16_f32 %0, %1, %2" : "=v"(u2) : "v"(e10), "v"(e11));
            asm("v_cvt_pk_bf16_f32 %0, %1, %2" : "=v"(u3) : "v"(e12), "v"(e13));
            pk[t * 4 + 0] = u0;
            pk[t * 4 + 1] = u1;
            pk[t * 4 + 2] = u2;
            pk[t * 4 + 3] = u3;
        }

        // ---- reduce: in-wave, then cross-wave (1 barrier per strip) ----
        {
            float s = ssum;
            s += __shfl_xor(s, 16);
            s += __shfl_xor(s, 32);
            if (lane < 16) sred[strip & 1][w][l15] = s;
        }
        __syncthreads();   // drains strip-1 stores (had a full sweep to finish)
        {
            const float rs = (sred[strip & 1][rg][l15] + sred[strip & 1][rg + 2][l15])
                           + (sred[strip & 1][rg + 4][l15] + sred[strip & 1][rg + 6][l15]);
            if (lane < 16) lds_inv[w][l15] = 1.0f / rs;
        }

        // ---- prefetch NEXT strip's K tile-0 + Q before stores (vmcnt ordering:
        //      loads older than stores -> next MFMA waits vmcnt(32), stores fly) ----
        if (strip < 3) {
            LDK_T0();
            LDQ(strip + 1);
        }

        // ---- store phase: wave-private transpose, contiguous nt stores, no waits ----
        short* pw = &lds_p[w][0];
        const int rowbase = qg * 128 + strip * 32 + rg * 16;
        const int colbase = cs * 32;
        const int rl = lane >> 3;       // 0..7
        const int cg = lane & 7;        // 0..7 (16B col group)

        #pragma unroll
        for (int t = 0; t < TILES; ++t) {
            #pragma unroll
            for (int sti = 0; sti < 2; ++sti) {
                uint2v uu;
                uu[0] = pk[t * 4 + sti * 2];
                uu[1] = pk[t * 4 + sti * 2 + 1];
                *reinterpret_cast<uint2v*>(&pw[l15 * PSTRIDE + sti * 16 + l4 * 4]) = uu;
            }
            #pragma unroll
            for (int sblk = 0; sblk < 2; ++sblk) {
                const int row = sblk * 8 + rl;
                uint2v uu = *reinterpret_cast<const uint2v*>(&pw[row * PSTRIDE + cg * 4]);
                const float invr = lds_inv[w][row];
                f32x4 pv = { bflo2f(uu[0]) * invr, bfhi2f(uu[0]) * invr,
                             bflo2f(uu[1]) * invr, bfhi2f(uu[1]) * invr };
                __builtin_nontemporal_store(pv,
                    reinterpret_cast<f32x4*>(outb + (size_t)(rowbase + row) * SEQ
                                             + t * 128 + colbase + cg * 4));
            }
        }
    }
#undef LDQ
#undef LDK_T0
}

// ---- fallback (no workspace): R10 structure, LDS-staged K from raw inputs ----
__global__ __launch_bounds__(512, 4)
void attn_fb_kernel(const float* __restrict__ Kp, const float* __restrict__ Qp,
                    const float* __restrict__ PKp, const float* __restrict__ PQp,
                    const int* __restrict__ maskp, float* __restrict__ out)
{
    __shared__ short lds_k[2][FRAG_SHORTS];
    __shared__ float lds_madd[SEQ];
    __shared__ short lds_p[8][16 * PSTRIDE];
    __shared__ float sred[8][16];
    __shared__ float lds_inv[8][16];

    const int p = blockIdx.x;
    const int x = p & 7;
    const int slot = p >> 3;
    const int bh = x + 8 * (slot >> 6);
    const int qb = slot & 63;

    const int tid = threadIdx.x;
    const int lane = tid & 63;
    const int w = tid >> 6;
    const int l15 = lane & 15;
    const int l4 = lane >> 4;
    const int rg = w & 1;
    const int cs = w >> 1;

    const int qrow = qb * 32 + rg * 16 + l15;

    const float* Qb  = Qp  + (size_t)bh * (SEQ * 64);
    const float* PQb = PQp + (size_t)bh * (SEQ * 32);
    const int*   mb  = maskp + (size_t)(bh >> 4) * SEQ;
    float* outb = out + (size_t)bh * SEQ * SEQ;

    bf16x8 qa[3];
    #pragma unroll
    for (int f = 0; f < 2; ++f) {
        const float* src = Qb + (size_t)qrow * 64 + f * 32 + l4 * 8;
        bf16x8 v;
        #pragma unroll
        for (int j = 0; j < 8; ++j) v[j] = f2bf(clip5(src[j]) * QS_C);
        qa[f] = v;
    }
    {
        const float* src = PQb + (size_t)qrow * 32 + l4 * 8;
        bf16x8 v;
        #pragma unroll
        for (int j = 0; j < 8; ++j) v[j] = f2bf(clip5(src[j]) * PQS_C);
        qa[2] = v;
    }

    #pragma unroll
    for (int i = 0; i < SEQ / 512; ++i) {
        int idx = i * 512 + tid;
        lds_madd[idx] = (mb[idx] ? -1e30f : 0.0f) - SHIFT_C;
    }

#define STAGE_FB(T, B) do {                                                                \
    const int tile0 = (T) * 128;                                                           \
    _Pragma("unroll")                                                                      \
    for (int i = 0; i < 6; ++i) {                                                          \
        int e = i * 512 + tid;                                                             \
        int col = e / 24, dq = e - col * 24, d0 = dq * 4;                                   \
        int colg = tile0 + col;                                                            \
        float4 v; int f, dd;                                                               \
        if (d0 < 64) {                                                                     \
            v = *reinterpret_cast<const float4*>(Kp + (size_t)bh * (SEQ * 64) + (size_t)colg * 64 + d0); \
            f = d0 >> 5; dd = d0 & 31;                                                     \
        } else {                                                                           \
            v = *reinterpret_cast<const float4*>(PKp + (size_t)bh * (SEQ * 32) + (size_t)colg * 32 + (d0 - 64)); \
            f = 2; dd = d0 - 64;                                                           \
        }                                                                                  \
        int ll = (col & 15) | ((dd >> 3) << 4);                                            \
        int st2 = col >> 4, j = dd & 7;                                                    \
        short4v s4;                                                                        \
        s4[0] = f2bf(clip5(v.x)); s4[1] = f2bf(clip5(v.y));                                \
        s4[2] = f2bf(clip5(v.z)); s4[3] = f2bf(clip5(v.w));                                \
        *reinterpret_cast<short4v*>(&lds_k[(B)][(((st2 * 3 + f) * 64 + ll) << 3) + j]) = s4; \
    }                                                                                      \
} while (0)

    unsigned pk[64];
    float ssum = 0.0f;

    STAGE_FB(0, 0);
    __syncthreads();

    #pragma unroll
    for (int t = 0; t < TILES; ++t) {
        if (t + 1 < TILES) STAGE_FB(t + 1, (t + 1) & 1);
        const short* lk = &lds_k[t & 1][0];
        #pragma unroll
        for (int sti = 0; sti < 2; ++sti) {
            const int st = cs * 2 + sti;
            bf16x8 kb0 = *reinterpret_cast<const bf16x8*>(lk + ((st * 3 + 0) * 64 + lane) * 8);
            bf16x8 kb1 = *reinterpret_cast<const bf16x8*>(lk + ((st * 3 + 1) * 64 + lane) * 8);
            bf16x8 kb2 = *reinterpret_cast<const bf16x8*>(lk + ((st * 3 + 2) * 64 + lane) * 8);
            f32x4 madd4 = *reinterpret_cast<const f32x4*>(&lds_madd[t * 128 + st * 16 + l4 * 4]);
            f32x4 acc = {0.f, 0.f, 0.f, 0.f};
            acc = __builtin_amdgcn_mfma_f32_16x16x32_bf16(kb0, qa[0], acc, 0, 0, 0);
            acc = __builtin_amdgcn_mfma_f32_16x16x32_bf16(kb1, qa[1], acc, 0, 0, 0);
            acc = __builtin_amdgcn_mfma_f32_16x16x32_bf16(kb2, qa[2], acc, 0, 0, 0);
            float e0 = exp2f(acc[0] + madd4[0]);
            float e1 = exp2f(acc[1] + madd4[1]);
            float e2 = exp2f(acc[2] + madd4[2]);
            float e3 = exp2f(acc[3] + madd4[3]);
            ssum += (e0 + e1) + (e2 + e3);
            unsigned u0, u1;
            asm("v_cvt_pk_bf16_f32 %0, %1, %2" : "=v"(u0) : "v"(e0), "v"(e1));
            asm("v_cvt_pk_bf16_f32 %0, %1, %2" : "=v"(u1) : "v"(e2), "v"(e3));
            pk[t * 4 + sti * 2]     = u0;
            pk[t * 4 + sti * 2 + 1] = u1;
        }
        __syncthreads();
    }

    {
        float s = ssum;
        s += __shfl_xor(s, 16);
        s += __shfl_xor(s, 32);
        if (lane < 16) sred[w][l15] = s;
    }
    __syncthreads();
    {
        const float rs = (sred[rg][l15] + sred[rg + 2][l15])
                       + (sred[rg + 4][l15] + sred[rg + 6][l15]);
        if (lane < 16) lds_inv[w][l15] = 1.0f / rs;
    }

    short* pw = &lds_p[w][0];
    const int rowbase = qb * 32 + rg * 16;
    const int colbase = cs * 32;
    const int rl = lane >> 3;
    const int cg = lane & 7;

    #pragma unroll
    for (int t = 0; t < TILES; ++t) {
        #pragma unroll
        for (int sti = 0; sti < 2; ++sti) {
            uint2v uu;
            uu[0] = pk[t * 4 + sti * 2];
            uu[1] = pk[t * 4 + sti * 2 + 1];
            *reinterpret_cast<uint2v*>(&pw[l15 * PSTRIDE + sti * 16 + l4 * 4]) = uu;
        }
        #pragma unroll
        for (int sblk = 0; sblk < 2; ++sblk) {
            const int row = sblk * 8 + rl;
            uint2v uu = *reinterpret_cast<const uint2v*>(&pw[row * PSTRIDE + cg * 4]);
            const float invr = lds_inv[w][row];
            f32x4 pv = { bflo2f(uu[0]) * invr, bfhi2f(uu[0]) * invr,
                         bflo2f(uu[1]) * invr, bfhi2f(uu[1]) * invr };
            __builtin_nontemporal_store(pv,
                reinterpret_cast<f32x4*>(outb + (size_t)(rowbase + row) * SEQ
                                         + t * 128 + colbase + cg * 4));
        }
    }
#undef STAGE_FB
}

extern "C" void kernel_launch(void* const* d_in, const int* in_sizes, int n_in,
                              void* d_out, int out_size, void* d_ws, size_t ws_size,
                              hipStream_t stream) {
    const float* keys      = (const float*)d_in[0];
    const float* queries   = (const float*)d_in[1];
    const float* pos_key   = (const float*)d_in[2];
    const float* pos_query = (const float*)d_in[3];
    const int*   mask      = (const int*)d_in[4];
    float* outp = (float*)d_out;

    const size_t need = (size_t)32 * TILES * FRAG_SHORTS * sizeof(short); // 12.58 MB
    if (ws_size >= need) {
        short* wsK = (short*)d_ws;
        prep_kernel<<<dim3(6144), dim3(256), 0, stream>>>(keys, pos_key, wsK);
        attn_ws_kernel<<<dim3(512), dim3(512), 0, stream>>>(
            queries, pos_query, mask, wsK, outp);
    } else {
        attn_fb_kernel<<<dim3(2048), dim3(512), 0, stream>>>(
            keys, queries, pos_key, pos_query, mask, outp);
    }
}

// Round 12
// 228.105 us; speedup vs baseline: 2.0366x; 2.0366x over previous
//
#include <hip/hip_runtime.h>
#include <cstdint>
#include <cstddef>

#define SEQ 2048
#define TILES 16
#define FRAG_SHORTS 12288                 // bf16 per 128-col tile (8 st * 3 frag * 64 lane * 8)
#define FRAG_BYTES  24576
#define PST 132                           // shorts per row of transpose buf (264 B)
#define PSTRIDE 36                        // fb kernel's transpose stride

typedef __attribute__((ext_vector_type(8))) short bf16x8;
typedef __attribute__((ext_vector_type(4))) float f32x4;
typedef __attribute__((ext_vector_type(4))) short short4v;
typedef __attribute__((ext_vector_type(2))) unsigned uint2v;

__device__ __forceinline__ short f2bf(float f) {
    union { float f; unsigned u; } a; a.f = f;
    unsigned r = a.u + 0x7fffu + ((a.u >> 16) & 1u);
    return (short)(r >> 16);
}
__device__ __forceinline__ float clip5(float v) { return fminf(fmaxf(v, -5.0f), 5.0f); }
__device__ __forceinline__ float bflo2f(unsigned u) { union { unsigned u; float f; } a; a.u = u << 16; return a.f; }
__device__ __forceinline__ float bfhi2f(unsigned u) { union { unsigned u; float f; } a; a.u = u & 0xffff0000u; return a.f; }

#define QS_C  (0.125f * 1.4426950408889634f)
#define PQS_C (0.17677669529663687f * 1.4426950408889634f)
#define SHIFT_C 28.853900817779268f

// ---- prepass: K/PK f32 -> clipped bf16 in MFMA A-fragment order ----
// ws layout: [bh(32)][tile(16)][st(8)][frag(3)][lane(64)][j(8)]
__global__ __launch_bounds__(256)
void prep_kernel(const float* __restrict__ Kp, const float* __restrict__ PKp,
                 short* __restrict__ wsK)
{
    int id = blockIdx.x * 256 + threadIdx.x;   // 65536 rows * 24 float4
    int q = id % 24;
    int row = id / 24;            // bh*2048 + col
    int bh = row >> 11;
    int col = row & 2047;
    int tile = col >> 7;
    int st = (col >> 4) & 7;
    int l15 = col & 15;
    float4 v;
    int f, dd;
    if (q < 16) {
        v = reinterpret_cast<const float4*>(Kp)[(size_t)row * 16 + q];
        f = q >> 3;
        dd = (q & 7) * 4;
    } else {
        v = reinterpret_cast<const float4*>(PKp)[(size_t)row * 8 + (q - 16)];
        f = 2;
        dd = (q - 16) * 4;
    }
    int ll = l15 | ((dd >> 3) << 4);
    int j = dd & 7;
    short4v s4;
    s4[0] = f2bf(clip5(v.x)); s4[1] = f2bf(clip5(v.y));
    s4[2] = f2bf(clip5(v.z)); s4[3] = f2bf(clip5(v.w));
    *reinterpret_cast<short4v*>(wsK + ((size_t)bh * TILES + tile) * FRAG_SHORTS
                                + (((st * 3 + f) * 64 + ll) << 3) + j) = s4;
}

// ---- pipelined main kernel: 1024 blocks x 512 thr (8 waves). Block: (bh, 64
// q rows) = 4 strips of 16 rows. Wave w owns subtile column st=w.
// Per strip sweep, tile t: [stage L(t+1)] [vmcnt(4) counted wait] [ds_write
// prev-P] [MFMA+exp+pack cur] [lgkm0 + raw barrier] [ds_read rows + 1 nt
// store of prev strip]. Stores trickle continuously; K staging is wave-local.
__global__ __launch_bounds__(512, 4)
void attn_pipe_kernel(const float* __restrict__ Qp, const float* __restrict__ PQp,
                      const int* __restrict__ maskp, const short* __restrict__ wsK,
                      float* __restrict__ out)
{
    __shared__ short lds_k[2][FRAG_SHORTS];   // 48 KiB dbuf (wave-local sections)
    __shared__ float lds_madd[SEQ];           // (mask? -1e30:0) - SHIFT
    __shared__ short lds_p[2][16 * PST];      // 8.25 KiB parity-dbuf transpose
    __shared__ float sred[8][16];
    __shared__ float lds_inv[16];

    const int p = blockIdx.x;
    const int x = p & 7;
    const int slot = p >> 3;               // 0..127
    const int bh = x + 8 * (slot >> 5);    // {x, x+8, x+16, x+24}
    const int qg = slot & 31;              // 64-row group

    const int tid = threadIdx.x;
    const int lane = tid & 63;
    const int w = tid >> 6;
    const int l15 = lane & 15;
    const int l4 = lane >> 4;

    const float* Qb  = Qp  + (size_t)bh * (SEQ * 64);
    const float* PQb = PQp + (size_t)bh * (SEQ * 32);
    const int*   mb  = maskp + (size_t)(bh >> 4) * SEQ;
    float* outb = out + (size_t)bh * SEQ * SEQ;

    // ---- mask -> LDS once ----
    #pragma unroll
    for (int i = 0; i < SEQ / 512; ++i) {
        int idx = i * 512 + tid;
        lds_madd[idx] = (mb[idx] ? -1e30f : 0.0f) - SHIFT_C;
    }

    const short* kf = wsK + (size_t)bh * (TILES * FRAG_SHORTS);

#define STAGE(T, B) do {                                                                   \
    const char* ksrc = (const char*)kf + (size_t)(T) * FRAG_BYTES;                         \
    _Pragma("unroll")                                                                      \
    for (int c = 0; c < 3; ++c) {                                                          \
        int off = w * 3072 + c * 1024;                                                     \
        __builtin_amdgcn_global_load_lds(                                                  \
            (const __attribute__((address_space(1))) void*)(ksrc + off + lane * 16),       \
            (__attribute__((address_space(3))) void*)((char*)&lds_k[(B)][0] + off),        \
            16, 0, 0);                                                                     \
    }                                                                                      \
} while (0)

#define LDQ(S) do {                                                                        \
    const int qrow_ = qg * 64 + (S) * 16 + l15;                                            \
    _Pragma("unroll")                                                                      \
    for (int f = 0; f < 2; ++f) {                                                          \
        const float4* s4p = reinterpret_cast<const float4*>(Qb + (size_t)qrow_ * 64 + f * 32 + l4 * 8); \
        float4 va = s4p[0], vb = s4p[1];                                                   \
        bf16x8 v;                                                                          \
        v[0] = f2bf(clip5(va.x) * QS_C); v[1] = f2bf(clip5(va.y) * QS_C);                  \
        v[2] = f2bf(clip5(va.z) * QS_C); v[3] = f2bf(clip5(va.w) * QS_C);                  \
        v[4] = f2bf(clip5(vb.x) * QS_C); v[5] = f2bf(clip5(vb.y) * QS_C);                  \
        v[6] = f2bf(clip5(vb.z) * QS_C); v[7] = f2bf(clip5(vb.w) * QS_C);                  \
        qa[f] = v;                                                                         \
    }                                                                                      \
    {                                                                                      \
        const float4* s4p = reinterpret_cast<const float4*>(PQb + (size_t)qrow_ * 32 + l4 * 8); \
        float4 va = s4p[0], vb = s4p[1];                                                   \
        bf16x8 v;                                                                          \
        v[0] = f2bf(clip5(va.x) * PQS_C); v[1] = f2bf(clip5(va.y) * PQS_C);                \
        v[2] = f2bf(clip5(va.z) * PQS_C); v[3] = f2bf(clip5(va.w) * PQS_C);                \
        v[4] = f2bf(clip5(vb.x) * PQS_C); v[5] = f2bf(clip5(vb.y) * PQS_C);                \
        v[6] = f2bf(clip5(vb.z) * PQS_C); v[7] = f2bf(clip5(vb.w) * PQS_C);                \
        qa[2] = v;                                                                         \
    }                                                                                      \
} while (0)

// One strip sweep. PKC: cur pk array; PKP: prev pk array; HS: has stores;
// WAITA: counted-vmcnt asm; SPREV: prev strip index (for store rows).
#define SWEEP(PKC, PKP, HS, WAITA, SPREV) do {                                             \
    float ssum = 0.0f;                                                                     \
    _Pragma("unroll")                                                                      \
    for (int t = 0; t < TILES; ++t) {                                                      \
        STAGE((t + 1) & 15, (t + 1) & 1);                                                  \
        asm volatile(WAITA ::: "memory");                                                  \
        __builtin_amdgcn_sched_barrier(0);                                                 \
        if (HS) {                                                                          \
            uint2v uu; uu[0] = PKP[t * 2]; uu[1] = PKP[t * 2 + 1];                         \
            *reinterpret_cast<uint2v*>(&lds_p[t & 1][l15 * PST + w * 16 + l4 * 4]) = uu;   \
        }                                                                                  \
        const short* lk = &lds_k[t & 1][0];                                                \
        bf16x8 kb0 = *reinterpret_cast<const bf16x8*>(lk + ((w * 3 + 0) * 64 + lane) * 8); \
        bf16x8 kb1 = *reinterpret_cast<const bf16x8*>(lk + ((w * 3 + 1) * 64 + lane) * 8); \
        bf16x8 kb2 = *reinterpret_cast<const bf16x8*>(lk + ((w * 3 + 2) * 64 + lane) * 8); \
        f32x4 m4 = *reinterpret_cast<const f32x4*>(&lds_madd[t * 128 + w * 16 + l4 * 4]);  \
        f32x4 acc = {0.f, 0.f, 0.f, 0.f};                                                  \
        acc = __builtin_amdgcn_mfma_f32_16x16x32_bf16(kb0, qa[0], acc, 0, 0, 0);           \
        acc = __builtin_amdgcn_mfma_f32_16x16x32_bf16(kb1, qa[1], acc, 0, 0, 0);           \
        acc = __builtin_amdgcn_mfma_f32_16x16x32_bf16(kb2, qa[2], acc, 0, 0, 0);           \
        float e0 = exp2f(acc[0] + m4[0]);                                                  \
        float e1 = exp2f(acc[1] + m4[1]);                                                  \
        float e2 = exp2f(acc[2] + m4[2]);                                                  \
        float e3 = exp2f(acc[3] + m4[3]);                                                  \
        ssum += (e0 + e1) + (e2 + e3);                                                     \
        unsigned u0, u1;                                                                   \
        asm("v_cvt_pk_bf16_f32 %0, %1, %2" : "=v"(u0) : "v"(e0), "v"(e1));                 \
        asm("v_cvt_pk_bf16_f32 %0, %1, %2" : "=v"(u1) : "v"(e2), "v"(e3));                 \
        PKC[t * 2]     = u0;                                                               \
        PKC[t * 2 + 1] = u1;                                                               \
        asm volatile("s_waitcnt lgkmcnt(0)" ::: "memory");                                 \
        __builtin_amdgcn_sched_barrier(0);                                                 \
        __builtin_amdgcn_s_barrier();                                                      \
        __builtin_amdgcn_sched_barrier(0);                                                 \
        if (HS) {                                                                          \
            const int row = w * 2 + (lane >> 5);                                           \
            uint2v uu = *reinterpret_cast<const uint2v*>(&lds_p[t & 1][row * PST + (lane & 31) * 4]); \
            const float invr = lds_inv[row];                                               \
            f32x4 pv = { bflo2f(uu[0]) * invr, bfhi2f(uu[0]) * invr,                       \
                         bflo2f(uu[1]) * invr, bfhi2f(uu[1]) * invr };                     \
            __builtin_nontemporal_store(pv,                                                \
                reinterpret_cast<f32x4*>(outb + (size_t)(qg * 64 + (SPREV) * 16 + row) * SEQ \
                                         + t * 128 + (lane & 31) * 4));                    \
        }                                                                                  \
    }                                                                                      \
    /* reduce this strip's row sums -> lds_inv (visible by next sweep's t0 barrier) */     \
    {                                                                                      \
        float s_ = ssum;                                                                   \
        s_ += __shfl_xor(s_, 16);                                                          \
        s_ += __shfl_xor(s_, 32);                                                          \
        if (lane < 16) sred[w][l15] = s_;                                                  \
        asm volatile("s_waitcnt lgkmcnt(0)" ::: "memory");                                 \
        __builtin_amdgcn_s_barrier();                                                      \
        __builtin_amdgcn_sched_barrier(0);                                                 \
        const float rs = ((sred[0][l15] + sred[1][l15]) + (sred[2][l15] + sred[3][l15]))   \
                       + ((sred[4][l15] + sred[5][l15]) + (sred[6][l15] + sred[7][l15]));  \
        if (w == 0 && lane < 16) lds_inv[l15] = 1.0f / rs;                                 \
    }                                                                                      \
} while (0)

    bf16x8 qa[3];
    unsigned pkE[32], pkO[32];

    // prologue: Q strip0, stage tile0, mask visible; full drain
    LDQ(0);
    STAGE(0, 0);
    __syncthreads();

    SWEEP(pkE, pkO, 0, "s_waitcnt vmcnt(3)", 0);
    LDQ(1);
    asm volatile("s_waitcnt vmcnt(0)" ::: "memory");
    __builtin_amdgcn_sched_barrier(0);
    SWEEP(pkO, pkE, 1, "s_waitcnt vmcnt(4)", 0);
    LDQ(2);
    asm volatile("s_waitcnt vmcnt(0)" ::: "memory");
    __builtin_amdgcn_sched_barrier(0);
    SWEEP(pkE, pkO, 1, "s_waitcnt vmcnt(4)", 1);
    LDQ(3);
    asm volatile("s_waitcnt vmcnt(0)" ::: "memory");
    __builtin_amdgcn_sched_barrier(0);
    SWEEP(pkO, pkE, 1, "s_waitcnt vmcnt(4)", 2);

    // ---- tail: store strip 3 (pkO) ----
    #pragma unroll
    for (int t = 0; t < TILES; ++t) {
        uint2v uu; uu[0] = pkO[t * 2]; uu[1] = pkO[t * 2 + 1];
        *reinterpret_cast<uint2v*>(&lds_p[t & 1][l15 * PST + w * 16 + l4 * 4]) = uu;
        __syncthreads();
        const int row = w * 2 + (lane >> 5);
        uint2v vv = *reinterpret_cast<const uint2v*>(&lds_p[t & 1][row * PST + (lane & 31) * 4]);
        const float invr = lds_inv[row];
        f32x4 pv = { bflo2f(vv[0]) * invr, bfhi2f(vv[0]) * invr,
                     bflo2f(vv[1]) * invr, bfhi2f(vv[1]) * invr };
        __builtin_nontemporal_store(pv,
            reinterpret_cast<f32x4*>(outb + (size_t)(qg * 64 + 48 + row) * SEQ
                                     + t * 128 + (lane & 31) * 4));
    }
#undef SWEEP
#undef LDQ
#undef STAGE
}

// ---- fallback (no workspace): R10 structure, LDS-staged K from raw inputs ----
__global__ __launch_bounds__(512, 4)
void attn_fb_kernel(const float* __restrict__ Kp, const float* __restrict__ Qp,
                    const float* __restrict__ PKp, const float* __restrict__ PQp,
                    const int* __restrict__ maskp, float* __restrict__ out)
{
    __shared__ short lds_k[2][FRAG_SHORTS];
    __shared__ float lds_madd[SEQ];
    __shared__ short lds_p[8][16 * PSTRIDE];
    __shared__ float sred[8][16];
    __shared__ float lds_inv[8][16];

    const int p = blockIdx.x;
    const int x = p & 7;
    const int slot = p >> 3;
    const int bh = x + 8 * (slot >> 6);
    const int qb = slot & 63;

    const int tid = threadIdx.x;
    const int lane = tid & 63;
    const int w = tid >> 6;
    const int l15 = lane & 15;
    const int l4 = lane >> 4;
    const int rg = w & 1;
    const int cs = w >> 1;

    const int qrow = qb * 32 + rg * 16 + l15;

    const float* Qb  = Qp  + (size_t)bh * (SEQ * 64);
    const float* PQb = PQp + (size_t)bh * (SEQ * 32);
    const int*   mb  = maskp + (size_t)(bh >> 4) * SEQ;
    float* outb = out + (size_t)bh * SEQ * SEQ;

    bf16x8 qa[3];
    #pragma unroll
    for (int f = 0; f < 2; ++f) {
        const float* src = Qb + (size_t)qrow * 64 + f * 32 + l4 * 8;
        bf16x8 v;
        #pragma unroll
        for (int j = 0; j < 8; ++j) v[j] = f2bf(clip5(src[j]) * QS_C);
        qa[f] = v;
    }
    {
        const float* src = PQb + (size_t)qrow * 32 + l4 * 8;
        bf16x8 v;
        #pragma unroll
        for (int j = 0; j < 8; ++j) v[j] = f2bf(clip5(src[j]) * PQS_C);
        qa[2] = v;
    }

    #pragma unroll
    for (int i = 0; i < SEQ / 512; ++i) {
        int idx = i * 512 + tid;
        lds_madd[idx] = (mb[idx] ? -1e30f : 0.0f) - SHIFT_C;
    }

#define STAGE_FB(T, B) do {                                                                \
    const int tile0 = (T) * 128;                                                           \
    _Pragma("unroll")                                                                      \
    for (int i = 0; i < 6; ++i) {                                                          \
        int e = i * 512 + tid;                                                             \
        int col = e / 24, dq = e - col * 24, d0 = dq * 4;                                   \
        int colg = tile0 + col;                                                            \
        float4 v; int f, dd;                                                               \
        if (d0 < 64) {                                                                     \
            v = *reinterpret_cast<const float4*>(Kp + (size_t)bh * (SEQ * 64) + (size_t)colg * 64 + d0); \
            f = d0 >> 5; dd = d0 & 31;                                                     \
        } else {                                                                           \
            v = *reinterpret_cast<const float4*>(PKp + (size_t)bh * (SEQ * 32) + (size_t)colg * 32 + (d0 - 64)); \
            f = 2; dd = d0 - 64;                                                           \
        }                                                                                  \
        int ll = (col & 15) | ((dd >> 3) << 4);                                            \
        int st2 = col >> 4, j = dd & 7;                                                    \
        short4v s4;                                                                        \
        s4[0] = f2bf(clip5(v.x)); s4[1] = f2bf(clip5(v.y));                                \
        s4[2] = f2bf(clip5(v.z)); s4[3] = f2bf(clip5(v.w));                                \
        *reinterpret_cast<short4v*>(&lds_k[(B)][(((st2 * 3 + f) * 64 + ll) << 3) + j]) = s4; \
    }                                                                                      \
} while (0)

    unsigned pk[64];
    float ssum = 0.0f;

    STAGE_FB(0, 0);
    __syncthreads();

    #pragma unroll
    for (int t = 0; t < TILES; ++t) {
        if (t + 1 < TILES) STAGE_FB(t + 1, (t + 1) & 1);
        const short* lk = &lds_k[t & 1][0];
        #pragma unroll
        for (int sti = 0; sti < 2; ++sti) {
            const int st = cs * 2 + sti;
            bf16x8 kb0 = *reinterpret_cast<const bf16x8*>(lk + ((st * 3 + 0) * 64 + lane) * 8);
            bf16x8 kb1 = *reinterpret_cast<const bf16x8*>(lk + ((st * 3 + 1) * 64 + lane) * 8);
            bf16x8 kb2 = *reinterpret_cast<const bf16x8*>(lk + ((st * 3 + 2) * 64 + lane) * 8);
            f32x4 madd4 = *reinterpret_cast<const f32x4*>(&lds_madd[t * 128 + st * 16 + l4 * 4]);
            f32x4 acc = {0.f, 0.f, 0.f, 0.f};
            acc = __builtin_amdgcn_mfma_f32_16x16x32_bf16(kb0, qa[0], acc, 0, 0, 0);
            acc = __builtin_amdgcn_mfma_f32_16x16x32_bf16(kb1, qa[1], acc, 0, 0, 0);
            acc = __builtin_amdgcn_mfma_f32_16x16x32_bf16(kb2, qa[2], acc, 0, 0, 0);
            float e0 = exp2f(acc[0] + madd4[0]);
            float e1 = exp2f(acc[1] + madd4[1]);
            float e2 = exp2f(acc[2] + madd4[2]);
            float e3 = exp2f(acc[3] + madd4[3]);
            ssum += (e0 + e1) + (e2 + e3);
            unsigned u0, u1;
            asm("v_cvt_pk_bf16_f32 %0, %1, %2" : "=v"(u0) : "v"(e0), "v"(e1));
            asm("v_cvt_pk_bf16_f32 %0, %1, %2" : "=v"(u1) : "v"(e2), "v"(e3));
            pk[t * 4 + sti * 2]     = u0;
            pk[t * 4 + sti * 2 + 1] = u1;
        }
        __syncthreads();
    }

    {
        float s = ssum;
        s += __shfl_xor(s, 16);
        s += __shfl_xor(s, 32);
        if (lane < 16) sred[w][l15] = s;
    }
    __syncthreads();
    {
        const float rs = (sred[rg][l15] + sred[rg + 2][l15])
                       + (sred[rg + 4][l15] + sred[rg + 6][l15]);
        if (lane < 16) lds_inv[w][l15] = 1.0f / rs;
    }

    short* pw = &lds_p[w][0];
    const int rowbase = qb * 32 + rg * 16;
    const int colbase = cs * 32;
    const int rl = lane >> 3;
    const int cg = lane & 7;

    #pragma unroll
    for (int t = 0; t < TILES; ++t) {
        #pragma unroll
        for (int sti = 0; sti < 2; ++sti) {
            uint2v uu;
            uu[0] = pk[t * 4 + sti * 2];
            uu[1] = pk[t * 4 + sti * 2 + 1];
            *reinterpret_cast<uint2v*>(&pw[l15 * PSTRIDE + sti * 16 + l4 * 4]) = uu;
        }
        #pragma unroll
        for (int sblk = 0; sblk < 2; ++sblk) {
            const int row = sblk * 8 + rl;
            uint2v uu = *reinterpret_cast<const uint2v*>(&pw[row * PSTRIDE + cg * 4]);
            const float invr = lds_inv[w][row];
            f32x4 pv = { bflo2f(uu[0]) * invr, bfhi2f(uu[0]) * invr,
                         bflo2f(uu[1]) * invr, bfhi2f(uu[1]) * invr };
            __builtin_nontemporal_store(pv,
                reinterpret_cast<f32x4*>(outb + (size_t)(rowbase + row) * SEQ
                                         + t * 128 + colbase + cg * 4));
        }
    }
#undef STAGE_FB
}

extern "C" void kernel_launch(void* const* d_in, const int* in_sizes, int n_in,
                              void* d_out, int out_size, void* d_ws, size_t ws_size,
                              hipStream_t stream) {
    const float* keys      = (const float*)d_in[0];
    const float* queries   = (const float*)d_in[1];
    const float* pos_key   = (const float*)d_in[2];
    const float* pos_query = (const float*)d_in[3];
    const int*   mask      = (const int*)d_in[4];
    float* outp = (float*)d_out;

    const size_t need = (size_t)32 * TILES * FRAG_SHORTS * sizeof(short); // 12.58 MB
    if (ws_size >= need) {
        short* wsK = (short*)d_ws;
        prep_kernel<<<dim3(6144), dim3(256), 0, stream>>>(keys, pos_key, wsK);
        attn_pipe_kernel<<<dim3(1024), dim3(512), 0, stream>>>(
            queries, pos_query, mask, wsK, outp);
    } else {
        attn_fb_kernel<<<dim3(2048), dim3(512), 0, stream>>>(
            keys, queries, pos_key, pos_query, mask, outp);
    }
}

// Round 13
// 157.771 us; speedup vs baseline: 2.9446x; 1.4458x over previous
//
#include <hip/hip_runtime.h>
#include <cstdint>
#include <cstddef>

#define SEQ 2048
#define TILES 16
#define FRAG_SHORTS 12288                 // bf16 per 128-col tile (8 st * 3 frag * 64 lane * 8)
#define FRAG_BYTES  24576
#define PSTRIDE 36                        // shorts per row of wave-private transpose buf

typedef __attribute__((ext_vector_type(8))) short bf16x8;
typedef __attribute__((ext_vector_type(4))) float f32x4;
typedef __attribute__((ext_vector_type(4))) short short4v;
typedef __attribute__((ext_vector_type(2))) unsigned uint2v;

__device__ __forceinline__ short f2bf(float f) {
    union { float f; unsigned u; } a; a.f = f;
    unsigned r = a.u + 0x7fffu + ((a.u >> 16) & 1u);
    return (short)(r >> 16);
}
__device__ __forceinline__ float clip5(float v) { return fminf(fmaxf(v, -5.0f), 5.0f); }
__device__ __forceinline__ float bflo2f(unsigned u) { union { unsigned u; float f; } a; a.u = u << 16; return a.f; }
__device__ __forceinline__ float bfhi2f(unsigned u) { union { unsigned u; float f; } a; a.u = u & 0xffff0000u; return a.f; }

// ---- prepass: K/PK f32 -> clipped bf16 in MFMA A-fragment order ----
// ws layout: [bh(32)][tile(16)][st(8)][frag(3)][lane(64)][j(8)]
__global__ __launch_bounds__(256)
void prep_kernel(const float* __restrict__ Kp, const float* __restrict__ PKp,
                 short* __restrict__ wsK)
{
    int id = blockIdx.x * 256 + threadIdx.x;   // 65536 rows * 24 float4
    int q = id % 24;
    int row = id / 24;            // bh*2048 + col
    int bh = row >> 11;
    int col = row & 2047;
    int tile = col >> 7;
    int st = (col >> 4) & 7;
    int l15 = col & 15;
    float4 v;
    int f, dd;
    if (q < 16) {                 // keys: 16 float4 per row
        v = reinterpret_cast<const float4*>(Kp)[(size_t)row * 16 + q];
        f = q >> 3;
        dd = (q & 7) * 4;
    } else {                      // pos_key: 8 float4 per row
        v = reinterpret_cast<const float4*>(PKp)[(size_t)row * 8 + (q - 16)];
        f = 2;
        dd = (q - 16) * 4;
    }
    int ll = l15 | ((dd >> 3) << 4);
    int j = dd & 7;
    short4v s4;
    s4[0] = f2bf(clip5(v.x)); s4[1] = f2bf(clip5(v.y));
    s4[2] = f2bf(clip5(v.z)); s4[3] = f2bf(clip5(v.w));
    *reinterpret_cast<short4v*>(wsK + ((size_t)bh * TILES + tile) * FRAG_SHORTS
                                + (((st * 3 + f) * 64 + ll) << 3) + j) = s4;
}

// 2048 blocks x 512 thr (8 waves). Block: (bh, 32 q rows). Wave: rg=w&1 row
// half (16 rows), cs=w>>1 col quarter (32 cols per 128-col tile).
// Single compute sweep: P kept packed-bf16 in pk[64] VGPRs + row sums.
// Then a BARRIER-FREE store phase: per tile, transpose pk through a
// wave-private LDS buf and issue full-line contiguous nontemporal stores.
// NEW vs R10: co-resident-pair phase stagger. HW fills CUs round-robin, so
// co-resident blocks differ by 256 in blockIdx; the (idx>>8)-odd class sleeps
// ~8.5us so its compute phase overlaps the partner's store phase (HBM never
// idles). Deterministic fixed-work delay; no memory traffic.
template<bool USEWS>
__global__ __launch_bounds__(512, 4)
void attn_map_kernel(const float* __restrict__ Kp, const float* __restrict__ Qp,
                     const float* __restrict__ PKp, const float* __restrict__ PQp,
                     const int* __restrict__ maskp, const short* __restrict__ wsK,
                     float* __restrict__ out)
{
    __shared__ short lds_k[2][FRAG_SHORTS];   // 48 KiB double buffer
    __shared__ float lds_madd[SEQ];           // (mask? -1e30:0) - SHIFT, 8 KiB
    __shared__ short lds_p[8][16 * PSTRIDE];  // 9 KiB wave-private transpose bufs
    __shared__ float sred[8][16];             // cross-wave row-sum partials
    __shared__ float lds_inv[8][16];          // per-wave copy of 1/rowsum

    // ---- phase stagger: odd dispatch-round class delays ~8.5us ----
    if ((blockIdx.x >> 8) & 1) {
        #pragma unroll
        for (int i = 0; i < 5; ++i) __builtin_amdgcn_s_sleep(64);
    }

    // XCD-aware mapping: p%8 = XCD; 4 bh x 64 q-blocks per XCD.
    const int p = blockIdx.x;
    const int x = p & 7;
    const int slot = p >> 3;               // 0..255
    const int bh = x + 8 * (slot >> 6);    // {x, x+8, x+16, x+24}
    const int qb = slot & 63;              // 0..63

    const int tid = threadIdx.x;
    const int lane = tid & 63;
    const int w = tid >> 6;
    const int l15 = lane & 15;
    const int l4 = lane >> 4;
    const int rg = w & 1;
    const int cs = w >> 1;

    const int qrow = qb * 32 + rg * 16 + l15;

    const float* Qb  = Qp  + (size_t)bh * (SEQ * 64);
    const float* PQb = PQp + (size_t)bh * (SEQ * 32);
    const int*   mb  = maskp + (size_t)(bh >> 4) * SEQ;
    float* outb = out + (size_t)bh * SEQ * SEQ;

    const float QS  = 0.125f * 1.4426950408889634f;               // SCALE * log2(e)
    const float PQS = 0.17677669529663687f * 1.4426950408889634f; // REL_SCALE * log2(e)
    const float SHIFT = 28.853900817779268f;                      // 20 * log2(e)

    // ---- Q / PQ fragments (B operand): lane holds Q[qrow][l4*8 + j] ----
    bf16x8 qa[3];
    #pragma unroll
    for (int f = 0; f < 2; ++f) {
        const float* src = Qb + (size_t)qrow * 64 + f * 32 + l4 * 8;
        bf16x8 v;
        #pragma unroll
        for (int j = 0; j < 8; ++j) v[j] = f2bf(clip5(src[j]) * QS);
        qa[f] = v;
    }
    {
        const float* src = PQb + (size_t)qrow * 32 + l4 * 8;
        bf16x8 v;
        #pragma unroll
        for (int j = 0; j < 8; ++j) v[j] = f2bf(clip5(src[j]) * PQS);
        qa[2] = v;
    }

    // ---- mask -> LDS as additive floats, -SHIFT folded in ----
    #pragma unroll
    for (int i = 0; i < SEQ / 512; ++i) {
        int idx = i * 512 + tid;
        lds_madd[idx] = (mb[idx] ? -1e30f : 0.0f) - SHIFT;
    }

    const short* kf = USEWS ? (wsK + (size_t)bh * (TILES * FRAG_SHORTS)) : nullptr;

#define STAGE(T, B) do {                                                                   \
    if constexpr (USEWS) {                                                                 \
        const char* ksrc = (const char*)kf + (size_t)(T) * FRAG_BYTES;                     \
        _Pragma("unroll")                                                                  \
        for (int c = 0; c < 3; ++c) {                                                      \
            int off = w * 3072 + c * 1024;                                                 \
            __builtin_amdgcn_global_load_lds(                                              \
                (const __attribute__((address_space(1))) void*)(ksrc + off + lane * 16),   \
                (__attribute__((address_space(3))) void*)((char*)&lds_k[(B)][0] + off),    \
                16, 0, 0);                                                                 \
        }                                                                                  \
    } else {                                                                               \
        const int tile0 = (T) * 128;                                                       \
        _Pragma("unroll")                                                                  \
        for (int i = 0; i < 6; ++i) {                                                      \
            int e = i * 512 + tid;                                                         \
            int col = e / 24, dq = e - col * 24, d0 = dq * 4;                               \
            int colg = tile0 + col;                                                        \
            float4 v; int f, dd;                                                           \
            if (d0 < 64) {                                                                 \
                v = *reinterpret_cast<const float4*>(Kp + (size_t)bh * (SEQ * 64) + (size_t)colg * 64 + d0); \
                f = d0 >> 5; dd = d0 & 31;                                                 \
            } else {                                                                       \
                v = *reinterpret_cast<const float4*>(PKp + (size_t)bh * (SEQ * 32) + (size_t)colg * 32 + (d0 - 64)); \
                f = 2; dd = d0 - 64;                                                       \
            }                                                                              \
            int ll = (col & 15) | ((dd >> 3) << 4);                                        \
            int st2 = col >> 4, j = dd & 7;                                                \
            short4v s4;                                                                    \
            s4[0] = f2bf(clip5(v.x)); s4[1] = f2bf(clip5(v.y));                            \
            s4[2] = f2bf(clip5(v.z)); s4[3] = f2bf(clip5(v.w));                            \
            *reinterpret_cast<short4v*>(&lds_k[(B)][(((st2 * 3 + f) * 64 + ll) << 3) + j]) = s4; \
        }                                                                                  \
    }                                                                                      \
} while (0)

    unsigned pk[64];   // packed bf16 P: [tile(16)][sti(2)][pair(2)]
    float ssum = 0.0f;

    STAGE(0, 0);
    __syncthreads();

    // ---- single compute sweep (fully unrolled: pk indices must be static) ----
    #pragma unroll
    for (int t = 0; t < TILES; ++t) {
        if (t + 1 < TILES) STAGE(t + 1, (t + 1) & 1);
        const short* lk = &lds_k[t & 1][0];
        #pragma unroll
        for (int sti = 0; sti < 2; ++sti) {
            const int st = cs * 2 + sti;
            bf16x8 kb0 = *reinterpret_cast<const bf16x8*>(lk + ((st * 3 + 0) * 64 + lane) * 8);
            bf16x8 kb1 = *reinterpret_cast<const bf16x8*>(lk + ((st * 3 + 1) * 64 + lane) * 8);
            bf16x8 kb2 = *reinterpret_cast<const bf16x8*>(lk + ((st * 3 + 2) * 64 + lane) * 8);
            f32x4 madd4 = *reinterpret_cast<const f32x4*>(&lds_madd[t * 128 + st * 16 + l4 * 4]);
            f32x4 acc = {0.f, 0.f, 0.f, 0.f};
            acc = __builtin_amdgcn_mfma_f32_16x16x32_bf16(kb0, qa[0], acc, 0, 0, 0);
            acc = __builtin_amdgcn_mfma_f32_16x16x32_bf16(kb1, qa[1], acc, 0, 0, 0);
            acc = __builtin_amdgcn_mfma_f32_16x16x32_bf16(kb2, qa[2], acc, 0, 0, 0);
            float e0 = exp2f(acc[0] + madd4[0]);
            float e1 = exp2f(acc[1] + madd4[1]);
            float e2 = exp2f(acc[2] + madd4[2]);
            float e3 = exp2f(acc[3] + madd4[3]);
            ssum += (e0 + e1) + (e2 + e3);
            unsigned u0, u1;
            asm("v_cvt_pk_bf16_f32 %0, %1, %2" : "=v"(u0) : "v"(e0), "v"(e1));
            asm("v_cvt_pk_bf16_f32 %0, %1, %2" : "=v"(u1) : "v"(e2), "v"(e3));
            pk[t * 4 + sti * 2]     = u0;
            pk[t * 4 + sti * 2 + 1] = u1;
        }
        __syncthreads();
    }

    // ---- row-sum reduce: in-wave, then cross-wave (4 cs waves share rg) ----
    {
        float s = ssum;
        s += __shfl_xor(s, 16);
        s += __shfl_xor(s, 32);
        if (lane < 16) sred[w][l15] = s;
    }
    __syncthreads();
    {
        const float rs = (sred[rg][l15] + sred[rg + 2][l15])
                       + (sred[rg + 4][l15] + sred[rg + 6][l15]);
        if (lane < 16) lds_inv[w][l15] = 1.0f / rs;   // wave-private copy
    }

    // ---- store phase: NO barriers. Per tile: transpose via wave-private LDS,
    //      scale, full-line contiguous nontemporal stores. ----
    short* pw = &lds_p[w][0];
    const int rowbase = qb * 32 + rg * 16;
    const int colbase = cs * 32;
    const int rl = lane >> 3;       // 0..7 (row within 8-row group)
    const int cg = lane & 7;        // 0..7 (16B column group)

    #pragma unroll
    for (int t = 0; t < TILES; ++t) {
        #pragma unroll
        for (int sti = 0; sti < 2; ++sti) {
            uint2v uu;
            uu[0] = pk[t * 4 + sti * 2];
            uu[1] = pk[t * 4 + sti * 2 + 1];
            *reinterpret_cast<uint2v*>(&pw[l15 * PSTRIDE + sti * 16 + l4 * 4]) = uu;
        }
        #pragma unroll
        for (int sblk = 0; sblk < 2; ++sblk) {
            const int row = sblk * 8 + rl;                  // local row 0..15
            uint2v uu = *reinterpret_cast<const uint2v*>(&pw[row * PSTRIDE + cg * 4]);
            const float invr = lds_inv[w][row];
            f32x4 pv = { bflo2f(uu[0]) * invr, bfhi2f(uu[0]) * invr,
                         bflo2f(uu[1]) * invr, bfhi2f(uu[1]) * invr };
            __builtin_nontemporal_store(pv,
                reinterpret_cast<f32x4*>(outb + (size_t)(rowbase + row) * SEQ
                                         + t * 128 + colbase + cg * 4));
        }
    }
#undef STAGE
}

extern "C" void kernel_launch(void* const* d_in, const int* in_sizes, int n_in,
                              void* d_out, int out_size, void* d_ws, size_t ws_size,
                              hipStream_t stream) {
    const float* keys      = (const float*)d_in[0];
    const float* queries   = (const float*)d_in[1];
    const float* pos_key   = (const float*)d_in[2];
    const float* pos_query = (const float*)d_in[3];
    const int*   mask      = (const int*)d_in[4];
    float* outp = (float*)d_out;

    const size_t need = (size_t)32 * TILES * FRAG_SHORTS * sizeof(short); // 12.58 MB
    if (ws_size >= need) {
        short* wsK = (short*)d_ws;
        prep_kernel<<<dim3(6144), dim3(256), 0, stream>>>(keys, pos_key, wsK);
        attn_map_kernel<true><<<dim3(2048), dim3(512), 0, stream>>>(
            keys, queries, pos_key, pos_query, mask, wsK, outp);
    } else {
        attn_map_kernel<false><<<dim3(2048), dim3(512), 0, stream>>>(
            keys, queries, pos_key, pos_query, mask, nullptr, outp);
    }
}